// Round 1
// baseline (85.870 us; speedup 1.0000x reference)
//
#include <hip/hip_runtime.h>

// VIN forward: B=1024, H=W=64, K=10 VI sweeps, then 36->256->256->5 MLP.
// One block per batch sample. 256 threads, 16 cells/thread (cell = tid + 256k).
// p/rout live in registers (current-cell only); rin and v (double-buffered)
// live in LDS because neighbor cells read them.

#define GRID_H 64
#define GRID_W 64
#define NCELL  (GRID_H * GRID_W)
#define K_ITERS 10

__global__ __launch_bounds__(256) void vin_kernel(
    const float* __restrict__ obs,     // [B,64,64,3]
    const float* __restrict__ W_phi,   // [3,3]
    const float* __restrict__ b_phi,   // [3]
    const float* __restrict__ W1,      // [36,256]
    const float* __restrict__ b1,      // [256]
    const float* __restrict__ W2,      // [256,256]
    const float* __restrict__ b2,      // [256]
    const float* __restrict__ Wl,      // [256,5]
    const float* __restrict__ bl,      // [5]
    float* __restrict__ out)           // [B,5]
{
    const int b   = blockIdx.x;
    const int tid = threadIdx.x;

    __shared__ float v_s[2][NCELL];    // 32 KB: double-buffered value map
    __shared__ float rin_s[NCELL];     // 16 KB: phi[...,1] (neighbors read it)
    __shared__ float feats[36];
    __shared__ float h_s[256];
    __shared__ int   agent_pos;

    const float* ob = obs + (size_t)b * (NCELL * 3);

    // phi weights -> registers (scalar-cached loads, wave-uniform)
    const float w00 = W_phi[0], w01 = W_phi[1], w02 = W_phi[2];
    const float w10 = W_phi[3], w11 = W_phi[4], w12 = W_phi[5];
    const float w20 = W_phi[6], w21 = W_phi[7], w22 = W_phi[8];
    const float bp0 = b_phi[0], bp1 = b_phi[1], bp2 = b_phi[2];

    float p_r[16], rout_r[16];

    // Load obs, compute phi = relu(obs @ W_phi + b_phi), init v=0.
    #pragma unroll
    for (int k = 0; k < 16; ++k) {
        const int cell = tid + k * 256;
        const float o0 = ob[cell * 3 + 0];
        const float o1 = ob[cell * 3 + 1];
        const float o2 = ob[cell * 3 + 2];
        const float ph0 = fmaxf(o0 * w00 + o1 * w10 + o2 * w20 + bp0, 0.0f);
        const float ph1 = fmaxf(o0 * w01 + o1 * w11 + o2 * w21 + bp1, 0.0f);
        const float ph2 = fmaxf(o0 * w02 + o1 * w12 + o2 * w22 + bp2, 0.0f);
        p_r[k]      = ph0;   // p
        rin_s[cell] = ph1;   // rin (neighbors read)
        rout_r[k]   = ph2;   // rout (current cell only)
        v_s[0][cell] = 0.0f;
        if (o1 > 0.5f) agent_pos = cell;   // one-hot agent channel (exactly one writer)
    }
    __syncthreads();

    // K Jacobi sweeps of the Bellman max-update.
    // nv_d(i,j) = p(i,j)*v(nb) + rin(nb) - rout(i,j); best = max(v, nv_valid...)
    int cur = 0;
    for (int it = 0; it < K_ITERS; ++it) {
        const float* __restrict__ vc = v_s[cur];
        float*       __restrict__ vn = v_s[cur ^ 1];
        #pragma unroll
        for (int k = 0; k < 16; ++k) {
            const int cell = tid + k * 256;
            const int r = cell >> 6;
            const int c = cell & 63;
            const float p  = p_r[k];
            const float ro = rout_r[k];
            float best = vc[cell];
            if (r > 0)  { const int n = cell - 64; best = fmaxf(best, p * vc[n] + rin_s[n] - ro); }
            if (r < 63) { const int n = cell + 64; best = fmaxf(best, p * vc[n] + rin_s[n] - ro); }
            if (c > 0)  { const int n = cell - 1;  best = fmaxf(best, p * vc[n] + rin_s[n] - ro); }
            if (c < 63) { const int n = cell + 1;  best = fmaxf(best, p * vc[n] + rin_s[n] - ro); }
            vn[cell] = best;
        }
        __syncthreads();
        cur ^= 1;
    }
    // final v is in v_s[cur]

    // Build 36 features: 3x3 zero-padded windows of (1-walls), agent, goal, v
    // around the agent cell.
    if (tid < 36) {
        const int ar = agent_pos >> 6, ac = agent_pos & 63;
        const int g  = tid / 9;        // 0=walls(flipped),1=agent,2=goal,3=v
        const int o  = tid % 9;
        const int rr = ar + (o / 3) - 1;
        const int cc = ac + (o % 3) - 1;
        float val = 0.0f;
        if (rr >= 0 && rr < GRID_H && cc >= 0 && cc < GRID_W) {
            const int cell = rr * 64 + cc;
            if      (g == 0) val = 1.0f - ob[cell * 3 + 0];
            else if (g == 1) val = ob[cell * 3 + 1];
            else if (g == 2) val = ob[cell * 3 + 2];
            else             val = v_s[cur][cell];
        }
        feats[tid] = val;
    }
    __syncthreads();

    // MLP: 36->256 (thread tid owns output column tid)
    float acc = b1[tid];
    #pragma unroll
    for (int i = 0; i < 36; ++i) acc += feats[i] * W1[i * 256 + tid];
    h_s[tid] = acc;
    __syncthreads();

    // 256->256
    float acc2 = b2[tid];
    for (int i = 0; i < 256; ++i) acc2 += h_s[i] * W2[i * 256 + tid];
    __syncthreads();           // protect h_s before overwrite
    h_s[tid] = acc2;
    __syncthreads();

    // 256->5
    if (tid < 5) {
        float o = bl[tid];
        for (int i = 0; i < 256; ++i) o += h_s[i] * Wl[i * 5 + tid];
        out[b * 5 + tid] = o;
    }
}

extern "C" void kernel_launch(void* const* d_in, const int* in_sizes, int n_in,
                              void* d_out, int out_size, void* d_ws, size_t ws_size,
                              hipStream_t stream) {
    const float* obs   = (const float*)d_in[0];
    const float* W_phi = (const float*)d_in[1];
    const float* b_phi = (const float*)d_in[2];
    const float* W1    = (const float*)d_in[3];
    const float* b1    = (const float*)d_in[4];
    const float* W2    = (const float*)d_in[5];
    const float* b2    = (const float*)d_in[6];
    const float* Wl    = (const float*)d_in[7];
    const float* bl    = (const float*)d_in[8];
    float* out = (float*)d_out;

    vin_kernel<<<dim3(1024), dim3(256), 0, stream>>>(
        obs, W_phi, b_phi, W1, b1, W2, b2, Wl, bl, out);
}

// Round 2
// 47.150 us; speedup vs baseline: 1.8212x; 1.8212x over previous
//
#include <hip/hip_runtime.h>

// VIN forward: B=1024, 64x64 grid, K=10 VI sweeps, 36->256->256->5 MLP.
// Register-resident VI: one block per sample, lane = column (64 lanes),
// wave w owns rows [16w, 16w+16) as registers. Horizontal neighbors via
// __shfl (cross-lane), vertical via register k+-1; only the 2 boundary rows
// per wave go through a small double-buffered LDS exchange each iteration.

#define K_ITERS 10

__global__ __launch_bounds__(256, 4) void vin_kernel(
    const float* __restrict__ obs,     // [B,64,64,3]
    const float* __restrict__ W_phi,   // [3,3]
    const float* __restrict__ b_phi,   // [3]
    const float* __restrict__ W1,      // [36,256]
    const float* __restrict__ b1,      // [256]
    const float* __restrict__ W2,      // [256,256]
    const float* __restrict__ b2,      // [256]
    const float* __restrict__ Wl,      // [256,5]
    const float* __restrict__ bl,      // [5]
    float* __restrict__ out)           // [B,5]
{
    const int b   = blockIdx.x;
    const int tid = threadIdx.x;
    const int w   = tid >> 6;   // wave id: rows 16w .. 16w+15
    const int l   = tid & 63;   // lane = column

    __shared__ float v_s[64 * 64];         // 16 KB: final value map (gather only)
    __shared__ float bnd[2][2][4][64];     // 4 KB: [buf][top/bot][wave][col]
    __shared__ float feats[36];
    __shared__ float h_s[256];
    __shared__ int   agent_pos;

    const float* ob = obs + (size_t)b * (4096 * 3);

    // phi weights (uniform -> SGPRs). phi[...,d] = sum_c o_c * W_phi[c*3+d]
    const float w00 = W_phi[0], w01 = W_phi[1], w02 = W_phi[2];
    const float w10 = W_phi[3], w11 = W_phi[4], w12 = W_phi[5];
    const float w20 = W_phi[6], w21 = W_phi[7], w22 = W_phi[8];
    const float bp0 = b_phi[0], bp1 = b_phi[1], bp2 = b_phi[2];

    float v[16], p[16], rin[16], rout[16], rinL[16], rinR[16];

    // Coalesced load (lane-consecutive 12B) + phi in registers.
    #pragma unroll
    for (int k = 0; k < 16; ++k) {
        const int cell = (16 * w + k) * 64 + l;
        const float o0 = ob[cell * 3 + 0];
        const float o1 = ob[cell * 3 + 1];
        const float o2 = ob[cell * 3 + 2];
        p[k]    = fmaxf(fmaf(o2, w20, fmaf(o1, w10, fmaf(o0, w00, bp0))), 0.f);
        rin[k]  = fmaxf(fmaf(o2, w21, fmaf(o1, w11, fmaf(o0, w01, bp1))), 0.f);
        rout[k] = fmaxf(fmaf(o2, w22, fmaf(o1, w12, fmaf(o0, w02, bp2))), 0.f);
        v[k] = 0.f;
        if (o1 > 0.5f) agent_pos = cell;   // one-hot: single writer per block
    }

    // Static left/right rin (column l-1 / l+1) into registers.
    #pragma unroll
    for (int k = 0; k < 16; ++k) {
        rinL[k] = __shfl_up(rin[k], 1, 64);
        rinR[k] = __shfl_down(rin[k], 1, 64);
    }

    // Static rin boundary rows (row 16w-1 / 16w+16) via LDS, once.
    bnd[0][0][w][l] = rin[0];
    bnd[0][1][w][l] = rin[15];
    __syncthreads();
    const float rinU_b = (w > 0) ? bnd[0][1][w - 1][l] : 0.f;
    const float rinD_b = (w < 3) ? bnd[0][0][w + 1][l] : 0.f;
    __syncthreads();   // bnd[0] reused by iter 0

    // K Jacobi sweeps. Boundary-row exchange double-buffered: iter it uses
    // bnd[it&1]; the same slot is rewritten 2 iters later, and every wave's
    // reads of slot s precede its next-iter barrier, which precedes the
    // rewrite -> one barrier per iteration suffices.
    int buf = 0;
    for (int it = 0; it < K_ITERS; ++it) {
        bnd[buf][0][w][l] = v[0];
        bnd[buf][1][w][l] = v[15];
        __syncthreads();
        const float vU_b = (w > 0) ? bnd[buf][1][w - 1][l] : 0.f;
        const float vD_b = (w < 3) ? bnd[buf][0][w + 1][l] : 0.f;

        float vm1 = vU_b;   // old v at row above (Jacobi: save before overwrite)
        #pragma unroll
        for (int k = 0; k < 16; ++k) {
            const float vk  = v[k];
            const float vp1 = (k < 15) ? v[k + 1] : vD_b;
            const float vL  = __shfl_up(vk, 1, 64);    // column l-1
            const float vR  = __shfl_down(vk, 1, 64);  // column l+1
            float best = vk;
            // up (row-1). At the true grid edge the term is p*0+0-rout <= 0
            // <= best, so it can never win; mask kept only where free/uniform.
            {
                const float rn = (k == 0) ? rinU_b : rin[k - 1];
                best = fmaxf(best, fmaf(p[k], vm1, rn) - rout[k]);
            }
            // down (row+1)
            {
                const float rn = (k == 15) ? rinD_b : rin[k + 1];
                best = fmaxf(best, fmaf(p[k], vp1, rn) - rout[k]);
            }
            // left (col-1): shfl wraps at lane 0 -> must mask
            {
                const float t = fmaf(p[k], vL, rinL[k]) - rout[k];
                if (l > 0) best = fmaxf(best, t);
            }
            // right (col+1)
            {
                const float t = fmaf(p[k], vR, rinR[k]) - rout[k];
                if (l < 63) best = fmaxf(best, t);
            }
            v[k] = best;
            vm1 = vk;
        }
        buf ^= 1;
    }

    // Final v -> LDS for the window gather.
    #pragma unroll
    for (int k = 0; k < 16; ++k) v_s[(16 * w + k) * 64 + l] = v[k];
    __syncthreads();

    // 36 features: 3x3 zero-padded windows of (1-walls), agent, goal, v.
    if (tid < 36) {
        const int ap = agent_pos;
        const int ar = ap >> 6, ac = ap & 63;
        const int g  = tid / 9, o = tid % 9;
        const int rr = ar + o / 3 - 1;
        const int cc = ac + o % 3 - 1;
        float val = 0.f;
        if (rr >= 0 && rr < 64 && cc >= 0 && cc < 64) {
            const int cell = rr * 64 + cc;
            if      (g == 0) val = 1.f - ob[cell * 3 + 0];
            else if (g == 1) val = ob[cell * 3 + 1];
            else if (g == 2) val = ob[cell * 3 + 2];
            else             val = v_s[cell];
        }
        feats[tid] = val;
    }
    __syncthreads();

    // MLP (all linear, per SlimFC defaults): 36->256->256->5
    float acc = b1[tid];
    #pragma unroll
    for (int i = 0; i < 36; ++i) acc = fmaf(feats[i], W1[i * 256 + tid], acc);
    h_s[tid] = acc;
    __syncthreads();

    float acc2 = b2[tid];
    #pragma unroll 8
    for (int i = 0; i < 256; ++i) acc2 = fmaf(h_s[i], W2[i * 256 + tid], acc2);
    __syncthreads();
    h_s[tid] = acc2;
    __syncthreads();

    if (tid < 5) {
        float o5 = bl[tid];
        for (int i = 0; i < 256; ++i) o5 = fmaf(h_s[i], Wl[i * 5 + tid], o5);
        out[b * 5 + tid] = o5;
    }
}

extern "C" void kernel_launch(void* const* d_in, const int* in_sizes, int n_in,
                              void* d_out, int out_size, void* d_ws, size_t ws_size,
                              hipStream_t stream) {
    const float* obs   = (const float*)d_in[0];
    const float* W_phi = (const float*)d_in[1];
    const float* b_phi = (const float*)d_in[2];
    const float* W1    = (const float*)d_in[3];
    const float* b1    = (const float*)d_in[4];
    const float* W2    = (const float*)d_in[5];
    const float* b2    = (const float*)d_in[6];
    const float* Wl    = (const float*)d_in[7];
    const float* bl    = (const float*)d_in[8];
    float* out = (float*)d_out;

    vin_kernel<<<dim3(1024), dim3(256), 0, stream>>>(
        obs, W_phi, b_phi, W1, b1, W2, b2, Wl, bl, out);
}

// Round 3
// 42.510 us; speedup vs baseline: 2.0200x; 1.1092x over previous
//
#include <hip/hip_runtime.h>

// VIN forward, two kernels:
//  A) per-sample VI (grid 1024): register-resident value iteration, lane=column,
//     wave w owns rows [16w,16w+16). Horizontal neighbor exchange via DPP
//     wave_shr:1 / wave_shl:1 (VALU pipe, zero-fill at wave edge); vertical via
//     register k+-1; 2 boundary rows per wave via small double-buffered LDS.
//     Writes feats[b][36] to workspace.
//  B) MLP 36->256->256->5 (grid 256, 4 samples/block): W2 element reused 4x
//     in-register; L2 traffic for W2 drops 268MB -> 64MB.

#define K_ITERS 10

// lane i <- lane i-1 (column l-1), lane 0 <- 0.0f
__device__ __forceinline__ float shr1(float x) {
    int r = __builtin_amdgcn_update_dpp(0, __float_as_int(x), 0x138, 0xF, 0xF, true);
    return __int_as_float(r);
}
// lane i <- lane i+1 (column l+1), lane 63 <- 0.0f
__device__ __forceinline__ float shl1(float x) {
    int r = __builtin_amdgcn_update_dpp(0, __float_as_int(x), 0x130, 0xF, 0xF, true);
    return __int_as_float(r);
}

__global__ __launch_bounds__(256, 4) void vin_vi_kernel(
    const float* __restrict__ obs,     // [B,64,64,3]
    const float* __restrict__ W_phi,   // [3,3]
    const float* __restrict__ b_phi,   // [3]
    float* __restrict__ feats_out)     // [B,36]
{
    const int b   = blockIdx.x;
    const int tid = threadIdx.x;
    const int w   = tid >> 6;   // wave id: rows 16w .. 16w+15
    const int l   = tid & 63;   // lane = column

    __shared__ float v_s[64 * 64];       // 16 KB: final value map (gather only)
    __shared__ float bnd[2][2][4][64];   // 4 KB: [buf][top/bot][wave][col]
    __shared__ int   agent_pos;

    const float* ob = obs + (size_t)b * (4096 * 3);

    const float w00 = W_phi[0], w01 = W_phi[1], w02 = W_phi[2];
    const float w10 = W_phi[3], w11 = W_phi[4], w12 = W_phi[5];
    const float w20 = W_phi[6], w21 = W_phi[7], w22 = W_phi[8];
    const float bp0 = b_phi[0], bp1 = b_phi[1], bp2 = b_phi[2];

    float v[16], p[16], rin[16], rout[16];

    #pragma unroll
    for (int k = 0; k < 16; ++k) {
        const int cell = (16 * w + k) * 64 + l;
        const float o0 = ob[cell * 3 + 0];
        const float o1 = ob[cell * 3 + 1];
        const float o2 = ob[cell * 3 + 2];
        p[k]    = fmaxf(fmaf(o2, w20, fmaf(o1, w10, fmaf(o0, w00, bp0))), 0.f);
        rin[k]  = fmaxf(fmaf(o2, w21, fmaf(o1, w11, fmaf(o0, w01, bp1))), 0.f);
        rout[k] = fmaxf(fmaf(o2, w22, fmaf(o1, w12, fmaf(o0, w02, bp2))), 0.f);
        v[k] = 0.f;
        if (o1 > 0.5f) agent_pos = cell;   // one-hot agent: single writer
    }

    // Static rin boundary rows (row 16w-1 / 16w+16) via LDS, once.
    bnd[0][0][w][l] = rin[0];
    bnd[0][1][w][l] = rin[15];
    __syncthreads();
    const float rinU_b = (w > 0) ? bnd[0][1][w - 1][l] : 0.f;
    const float rinD_b = (w < 3) ? bnd[0][0][w + 1][l] : 0.f;
    __syncthreads();   // bnd[0] reused by iter 0

    // K Jacobi sweeps. All 4 edge cases are mask-free: v>=0 (monotone from 0),
    // p,rin,rout>=0 (relu), DPP zero-fill gives nb-v=0, nb-rin=0 at wave edges
    // -> edge term = -rout <= 0 <= v <= best, never wins.
    int buf = 0;
    for (int it = 0; it < K_ITERS; ++it) {
        bnd[buf][0][w][l] = v[0];
        bnd[buf][1][w][l] = v[15];
        __syncthreads();
        const float vU_b = (w > 0) ? bnd[buf][1][w - 1][l] : 0.f;
        const float vD_b = (w < 3) ? bnd[buf][0][w + 1][l] : 0.f;

        float vm1 = vU_b;   // old v at row above (Jacobi)
        #pragma unroll
        for (int k = 0; k < 16; ++k) {
            const float vk  = v[k];
            const float pk  = p[k];
            const float vp1 = (k < 15) ? v[k + 1] : vD_b;
            const float rp1 = (k < 15) ? rin[k + 1] : rinD_b;
            const float rm1 = (k > 0)  ? rin[k - 1] : rinU_b;
            const float vL = shr1(vk),     vR = shl1(vk);
            const float rL = shr1(rin[k]), rR = shl1(rin[k]);
            const float tU = fmaf(pk, vm1, rm1);
            const float tD = fmaf(pk, vp1, rp1);
            const float tL = fmaf(pk, vL, rL);
            const float tR = fmaf(pk, vR, rR);
            const float m  = fmaxf(fmaxf(fmaxf(tU, tD), tL), tR);
            v[k] = fmaxf(vk, m - rout[k]);
            vm1 = vk;
        }
        buf ^= 1;
    }

    #pragma unroll
    for (int k = 0; k < 16; ++k) v_s[(16 * w + k) * 64 + l] = v[k];
    __syncthreads();

    // 36 features: 3x3 zero-padded windows of (1-walls), agent, goal, v.
    if (tid < 36) {
        const int ap = agent_pos;
        const int ar = ap >> 6, ac = ap & 63;
        const int g  = tid / 9, o = tid % 9;
        const int rr = ar + o / 3 - 1;
        const int cc = ac + o % 3 - 1;
        float val = 0.f;
        if (rr >= 0 && rr < 64 && cc >= 0 && cc < 64) {
            const int cell = rr * 64 + cc;
            if      (g == 0) val = 1.f - ob[cell * 3 + 0];
            else if (g == 1) val = ob[cell * 3 + 1];
            else if (g == 2) val = ob[cell * 3 + 2];
            else             val = v_s[cell];
        }
        feats_out[b * 36 + tid] = val;
    }
}

__global__ __launch_bounds__(256) void vin_mlp_kernel(
    const float* __restrict__ feats,   // [B,36]
    const float* __restrict__ W1,      // [36,256]
    const float* __restrict__ b1,      // [256]
    const float* __restrict__ W2,      // [256,256]
    const float* __restrict__ b2,      // [256]
    const float* __restrict__ Wl,      // [256,5]
    const float* __restrict__ bl,      // [5]
    float* __restrict__ out)           // [B,5]
{
    const int b0  = blockIdx.x * 4;    // 4 samples per block
    const int tid = threadIdx.x;       // = output column c

    __shared__ float f_s[4][36];
    __shared__ __align__(16) float h1_s[256][4];   // [col][sample] for b128 bcast
    __shared__ float h2_s[4][256];
    __shared__ float red[8][4][5];     // [chunk][sample][logit]

    if (tid < 144) f_s[tid / 36][tid % 36] = feats[b0 * 36 + tid];
    __syncthreads();

    // 36 -> 256 (linear)
    float a1_0 = b1[tid], a1_1 = a1_0, a1_2 = a1_0, a1_3 = a1_0;
    #pragma unroll
    for (int i = 0; i < 36; ++i) {
        const float wv = W1[i * 256 + tid];
        a1_0 = fmaf(f_s[0][i], wv, a1_0);
        a1_1 = fmaf(f_s[1][i], wv, a1_1);
        a1_2 = fmaf(f_s[2][i], wv, a1_2);
        a1_3 = fmaf(f_s[3][i], wv, a1_3);
    }
    *reinterpret_cast<float4*>(&h1_s[tid][0]) = make_float4(a1_0, a1_1, a1_2, a1_3);
    __syncthreads();

    // 256 -> 256 (linear); W2 element reused 4x in-register
    float a2_0 = b2[tid], a2_1 = a2_0, a2_2 = a2_0, a2_3 = a2_0;
    #pragma unroll 8
    for (int i = 0; i < 256; ++i) {
        const float wv = W2[i * 256 + tid];
        const float4 h = *reinterpret_cast<const float4*>(&h1_s[i][0]); // bcast
        a2_0 = fmaf(h.x, wv, a2_0);
        a2_1 = fmaf(h.y, wv, a2_1);
        a2_2 = fmaf(h.z, wv, a2_2);
        a2_3 = fmaf(h.w, wv, a2_3);
    }
    h2_s[0][tid] = a2_0;
    h2_s[1][tid] = a2_1;
    h2_s[2][tid] = a2_2;
    h2_s[3][tid] = a2_3;
    __syncthreads();

    // 256 -> 5: 160 threads, each sums a 32-wide chunk for one (sample,logit)
    if (tid < 160) {
        const int s  = tid % 4;
        const int j  = (tid / 4) % 5;
        const int ch = tid / 20;
        float acc = 0.f;
        #pragma unroll
        for (int m = 0; m < 32; ++m) {
            const int i = ch * 32 + m;
            acc = fmaf(h2_s[s][i], Wl[i * 5 + j], acc);
        }
        red[ch][s][j] = acc;
    }
    __syncthreads();
    if (tid < 20) {
        const int s = tid % 4;
        const int j = tid / 4;
        float o = bl[j];
        #pragma unroll
        for (int ch = 0; ch < 8; ++ch) o += red[ch][s][j];
        out[(b0 + s) * 5 + j] = o;
    }
}

extern "C" void kernel_launch(void* const* d_in, const int* in_sizes, int n_in,
                              void* d_out, int out_size, void* d_ws, size_t ws_size,
                              hipStream_t stream) {
    const float* obs   = (const float*)d_in[0];
    const float* W_phi = (const float*)d_in[1];
    const float* b_phi = (const float*)d_in[2];
    const float* W1    = (const float*)d_in[3];
    const float* b1    = (const float*)d_in[4];
    const float* W2    = (const float*)d_in[5];
    const float* b2    = (const float*)d_in[6];
    const float* Wl    = (const float*)d_in[7];
    const float* bl    = (const float*)d_in[8];
    float* out   = (float*)d_out;
    float* feats = (float*)d_ws;   // 1024*36*4 = 147456 bytes

    vin_vi_kernel<<<dim3(1024), dim3(256), 0, stream>>>(obs, W_phi, b_phi, feats);
    vin_mlp_kernel<<<dim3(256), dim3(256), 0, stream>>>(feats, W1, b1, W2, b2, Wl, bl, out);
}

// Round 4
// 35.770 us; speedup vs baseline: 2.4006x; 1.1884x over previous
//
#include <hip/hip_runtime.h>

// VIN forward, two kernels:
//  A) per-sample VI (grid 1024, block 512): register-resident value iteration.
//     lane = column (64 lanes), wave w of 8 owns rows [8w, 8w+8) as registers
//     -> ~52 live floats/thread, fits VGPRs with headroom (R3's 16-row/wave
//     variant needed 66+ live floats but VGPR_Count=60 -> state was being
//     juggled through AGPRs/scratch; this kills that).
//     Horizontal neighbors via DPP wave_shr/wave_shl (VALU pipe, zero-fill);
//     vertical via register k+-1; 2 boundary rows per wave via small
//     double-buffered LDS exchange. Writes feats[b][36] to workspace.
//  B) MLP 36->256->256->5 (grid 256, block 512): 4 samples/block (W2 element
//     reused 4x in-register, 64MB L2 traffic) + split-K over 2 halves so each
//     SIMD has 2 waves and the W2 load chain is 128 long, not 256.

#define K_ITERS 10

// lane i <- lane i-1 (column l-1), lane 0 <- 0.0f  (wave_shr:1, bound_ctrl)
__device__ __forceinline__ float shr1(float x) {
    int r = __builtin_amdgcn_update_dpp(0, __float_as_int(x), 0x138, 0xF, 0xF, true);
    return __int_as_float(r);
}
// lane i <- lane i+1 (column l+1), lane 63 <- 0.0f  (wave_shl:1, bound_ctrl)
__device__ __forceinline__ float shl1(float x) {
    int r = __builtin_amdgcn_update_dpp(0, __float_as_int(x), 0x130, 0xF, 0xF, true);
    return __int_as_float(r);
}

__global__ __launch_bounds__(512, 4) void vin_vi_kernel(
    const float* __restrict__ obs,     // [B,64,64,3]
    const float* __restrict__ W_phi,   // [3,3]
    const float* __restrict__ b_phi,   // [3]
    float* __restrict__ feats_out)     // [B,36]
{
    const int b   = blockIdx.x;
    const int tid = threadIdx.x;
    const int w   = tid >> 6;   // wave id 0..7: rows 8w .. 8w+7
    const int l   = tid & 63;   // lane = column

    __shared__ float v_s[64 * 64];       // 16 KB: final value map (gather only)
    __shared__ float bnd[2][2][8][64];   // 8 KB: [buf][top/bot][wave][col]
    __shared__ int   agent_pos;

    const float* ob = obs + (size_t)b * (4096 * 3);

    const float w00 = W_phi[0], w01 = W_phi[1], w02 = W_phi[2];
    const float w10 = W_phi[3], w11 = W_phi[4], w12 = W_phi[5];
    const float w20 = W_phi[6], w21 = W_phi[7], w22 = W_phi[8];
    const float bp0 = b_phi[0], bp1 = b_phi[1], bp2 = b_phi[2];

    float v[8], p[8], rin[8], rout[8], rinL[8], rinR[8];

    #pragma unroll
    for (int k = 0; k < 8; ++k) {
        const int cell = (8 * w + k) * 64 + l;
        const float o0 = ob[cell * 3 + 0];
        const float o1 = ob[cell * 3 + 1];
        const float o2 = ob[cell * 3 + 2];
        p[k]    = fmaxf(fmaf(o2, w20, fmaf(o1, w10, fmaf(o0, w00, bp0))), 0.f);
        rin[k]  = fmaxf(fmaf(o2, w21, fmaf(o1, w11, fmaf(o0, w01, bp1))), 0.f);
        rout[k] = fmaxf(fmaf(o2, w22, fmaf(o1, w12, fmaf(o0, w02, bp2))), 0.f);
        v[k] = 0.f;
        if (o1 > 0.5f) agent_pos = cell;   // one-hot agent: single writer
    }

    // Loop-invariant: left/right-neighbor rin in registers (hoisted DPP).
    #pragma unroll
    for (int k = 0; k < 8; ++k) { rinL[k] = shr1(rin[k]); rinR[k] = shl1(rin[k]); }

    // Loop-invariant: rin rows at 8w-1 / 8w+8 via LDS, once.
    bnd[0][0][w][l] = rin[0];
    bnd[0][1][w][l] = rin[7];
    __syncthreads();
    const float rinU_b = (w > 0) ? bnd[0][1][w - 1][l] : 0.f;
    const float rinD_b = (w < 7) ? bnd[0][0][w + 1][l] : 0.f;
    __syncthreads();   // bnd[0] rewritten by iter 0

    // K Jacobi sweeps. Mask-free edges: v>=0 monotone, p/rin/rout>=0 (relu),
    // DPP zero-fill + zero boundary rows make every out-of-grid term
    // = -rout <= 0 <= v, so it never wins the max.
    int buf = 0;
    for (int it = 0; it < K_ITERS; ++it) {
        bnd[buf][0][w][l] = v[0];
        bnd[buf][1][w][l] = v[7];
        __syncthreads();
        const float vU_b = (w > 0) ? bnd[buf][1][w - 1][l] : 0.f;
        const float vD_b = (w < 7) ? bnd[buf][0][w + 1][l] : 0.f;

        float vm1 = vU_b;   // old v at row above (Jacobi)
        #pragma unroll
        for (int k = 0; k < 8; ++k) {
            const float vk  = v[k];
            const float pk  = p[k];
            const float vp1 = (k < 7) ? v[k + 1] : vD_b;
            const float rp1 = (k < 7) ? rin[k + 1] : rinD_b;
            const float rm1 = (k > 0) ? rin[k - 1] : rinU_b;
            const float vL  = shr1(vk);
            const float vR  = shl1(vk);
            const float tU  = fmaf(pk, vm1, rm1);
            const float tD  = fmaf(pk, vp1, rp1);
            const float tL  = fmaf(pk, vL, rinL[k]);
            const float tR  = fmaf(pk, vR, rinR[k]);
            const float m   = fmaxf(fmaxf(tU, tD), fmaxf(tL, tR));
            v[k] = fmaxf(vk, m - rout[k]);
            vm1 = vk;
        }
        buf ^= 1;
    }

    #pragma unroll
    for (int k = 0; k < 8; ++k) v_s[(8 * w + k) * 64 + l] = v[k];
    __syncthreads();

    // 36 features: 3x3 zero-padded windows of (1-walls), agent, goal, v.
    if (tid < 36) {
        const int ap = agent_pos;
        const int ar = ap >> 6, ac = ap & 63;
        const int g  = tid / 9, o = tid % 9;
        const int rr = ar + o / 3 - 1;
        const int cc = ac + o % 3 - 1;
        float val = 0.f;
        if (rr >= 0 && rr < 64 && cc >= 0 && cc < 64) {
            const int cell = rr * 64 + cc;
            if      (g == 0) val = 1.f - ob[cell * 3 + 0];
            else if (g == 1) val = ob[cell * 3 + 1];
            else if (g == 2) val = ob[cell * 3 + 2];
            else             val = v_s[cell];
        }
        feats_out[b * 36 + tid] = val;
    }
}

__global__ __launch_bounds__(512) void vin_mlp_kernel(
    const float* __restrict__ feats,   // [B,36]
    const float* __restrict__ W1,      // [36,256]
    const float* __restrict__ b1,      // [256]
    const float* __restrict__ W2,      // [256,256]
    const float* __restrict__ b2,      // [256]
    const float* __restrict__ Wl,      // [256,5]
    const float* __restrict__ bl,      // [5]
    float* __restrict__ out)           // [B,5]
{
    const int b0  = blockIdx.x * 4;    // 4 samples per block
    const int tid = threadIdx.x;
    const int c   = tid & 255;         // output column
    const int h   = tid >> 8;          // K-half 0/1

    __shared__ float f_s[4][36];
    __shared__ float part[2][4][256];              // [half][sample][col] 8KB
    __shared__ __align__(16) float h1_s[256][4];   // [col][sample] 4KB
    __shared__ __align__(16) float h2_s[4][256];   // 4KB
    __shared__ float red[8][4][5];

    if (tid < 144) f_s[tid / 36][tid % 36] = feats[b0 * 36 + tid];
    __syncthreads();

    // 36 -> 256 (linear), split-K: half h sums rows [18h, 18h+18)
    {
        float a0 = 0.f, a1 = 0.f, a2 = 0.f, a3 = 0.f;
        #pragma unroll
        for (int m = 0; m < 18; ++m) {
            const int i = 18 * h + m;
            const float wv = W1[i * 256 + c];
            a0 = fmaf(f_s[0][i], wv, a0);
            a1 = fmaf(f_s[1][i], wv, a1);
            a2 = fmaf(f_s[2][i], wv, a2);
            a3 = fmaf(f_s[3][i], wv, a3);
        }
        part[h][0][c] = a0; part[h][1][c] = a1;
        part[h][2][c] = a2; part[h][3][c] = a3;
    }
    __syncthreads();
    {   // combine: thread (c,h) produces samples 2h, 2h+1
        const int s0 = 2 * h, s1 = 2 * h + 1;
        const float bb = b1[c];
        h1_s[c][s0] = bb + part[0][s0][c] + part[1][s0][c];
        h1_s[c][s1] = bb + part[0][s1][c] + part[1][s1][c];
    }
    __syncthreads();

    // 256 -> 256 (linear), split-K: half h sums rows [128h, 128h+128)
    {
        float a0 = 0.f, a1 = 0.f, a2 = 0.f, a3 = 0.f;
        #pragma unroll 8
        for (int m = 0; m < 128; ++m) {
            const int i = 128 * h + m;
            const float wv = W2[i * 256 + c];
            const float4 hv = *reinterpret_cast<const float4*>(&h1_s[i][0]);
            a0 = fmaf(hv.x, wv, a0);
            a1 = fmaf(hv.y, wv, a1);
            a2 = fmaf(hv.z, wv, a2);
            a3 = fmaf(hv.w, wv, a3);
        }
        part[h][0][c] = a0; part[h][1][c] = a1;
        part[h][2][c] = a2; part[h][3][c] = a3;
    }
    __syncthreads();
    {
        const int s0 = 2 * h, s1 = 2 * h + 1;
        const float bb = b2[c];
        h2_s[s0][c] = bb + part[0][s0][c] + part[1][s0][c];
        h2_s[s1][c] = bb + part[0][s1][c] + part[1][s1][c];
    }
    __syncthreads();

    // 256 -> 5: 160 threads, each sums a 32-wide chunk for one (sample,logit)
    if (tid < 160) {
        const int s  = tid % 4;
        const int j  = (tid / 4) % 5;
        const int ch = tid / 20;
        float acc = 0.f;
        #pragma unroll
        for (int m = 0; m < 32; ++m) {
            const int i = ch * 32 + m;
            acc = fmaf(h2_s[s][i], Wl[i * 5 + j], acc);
        }
        red[ch][s][j] = acc;
    }
    __syncthreads();
    if (tid < 20) {
        const int s = tid % 4;
        const int j = tid / 4;
        float o = bl[j];
        #pragma unroll
        for (int ch = 0; ch < 8; ++ch) o += red[ch][s][j];
        out[(b0 + s) * 5 + j] = o;
    }
}

extern "C" void kernel_launch(void* const* d_in, const int* in_sizes, int n_in,
                              void* d_out, int out_size, void* d_ws, size_t ws_size,
                              hipStream_t stream) {
    const float* obs   = (const float*)d_in[0];
    const float* W_phi = (const float*)d_in[1];
    const float* b_phi = (const float*)d_in[2];
    const float* W1    = (const float*)d_in[3];
    const float* b1    = (const float*)d_in[4];
    const float* W2    = (const float*)d_in[5];
    const float* b2    = (const float*)d_in[6];
    const float* Wl    = (const float*)d_in[7];
    const float* bl    = (const float*)d_in[8];
    float* out   = (float*)d_out;
    float* feats = (float*)d_ws;   // 1024*36*4 = 147456 bytes

    vin_vi_kernel<<<dim3(1024), dim3(512), 0, stream>>>(obs, W_phi, b_phi, feats);
    vin_mlp_kernel<<<dim3(256), dim3(512), 0, stream>>>(feats, W1, b1, W2, b2, Wl, bl, out);
}

// Round 5
// 31.005 us; speedup vs baseline: 2.7695x; 1.1537x over previous
//
#include <hip/hip_runtime.h>

// VIN forward, two kernels:
//  A) per-sample VI (grid 1024, block 512): register-resident value iteration.
//     lane = column, wave w of 8 owns rows [8w,8w+8). Per-cell inner loop is
//     10 VALU: 2 single-inst DPP shifts (mov_dpp, zero-fill), 4 FMA against
//     pre-folded (rin_nb - rout) constants, 4 max. Iter 0 peeled (v==0 -> no
//     exchange); boundary-row ds_writes pipelined into the k-loop so only
//     barrier + 2 ds_reads sit on the inter-iteration critical path.
//  B) MLP 36->256->256->5 (grid 256, block 1024, 4 samples/block, 4-way
//     split-K): W2 L2 traffic stays 64MB, 4 waves/SIMD hide L2 latency.

#define K_ITERS 10

// lane i <- lane i-1 (column l-1), lane 0 <- 0.0f  (wave_shr:1, bound_ctrl:1)
__device__ __forceinline__ float shr1(float x) {
#if __has_builtin(__builtin_amdgcn_mov_dpp)
    return __int_as_float(__builtin_amdgcn_mov_dpp(__float_as_int(x), 0x138, 0xF, 0xF, true));
#else
    return __int_as_float(__builtin_amdgcn_update_dpp(0, __float_as_int(x), 0x138, 0xF, 0xF, true));
#endif
}
// lane i <- lane i+1 (column l+1), lane 63 <- 0.0f  (wave_shl:1, bound_ctrl:1)
__device__ __forceinline__ float shl1(float x) {
#if __has_builtin(__builtin_amdgcn_mov_dpp)
    return __int_as_float(__builtin_amdgcn_mov_dpp(__float_as_int(x), 0x130, 0xF, 0xF, true));
#else
    return __int_as_float(__builtin_amdgcn_update_dpp(0, __float_as_int(x), 0x130, 0xF, 0xF, true));
#endif
}

__global__ __launch_bounds__(512, 4) void vin_vi_kernel(
    const float* __restrict__ obs,     // [B,64,64,3]
    const float* __restrict__ W_phi,   // [3,3]
    const float* __restrict__ b_phi,   // [3]
    float* __restrict__ feats_out)     // [B,36]
{
    const int b   = blockIdx.x;
    const int tid = threadIdx.x;
    const int w   = tid >> 6;   // wave id 0..7: rows 8w .. 8w+7
    const int l   = tid & 63;   // lane = column

    __shared__ float v_s[64 * 64];       // 16 KB (final value map, gather only)
    __shared__ float bnd[2][2][8][64];   // 8 KB: v boundary rows [buf][top/bot][wave][col]
    __shared__ float rbnd[2][8][64];     // 2 KB: rin boundary rows (static)
    __shared__ int   agent_pos;

    const float* ob = obs + (size_t)b * (4096 * 3);

    const float w00 = W_phi[0], w01 = W_phi[1], w02 = W_phi[2];
    const float w10 = W_phi[3], w11 = W_phi[4], w12 = W_phi[5];
    const float w20 = W_phi[6], w21 = W_phi[7], w22 = W_phi[8];
    const float bp0 = b_phi[0], bp1 = b_phi[1], bp2 = b_phi[2];

    float p[8], rin[8], rout[8];

    #pragma unroll
    for (int k = 0; k < 8; ++k) {
        const int cell = (8 * w + k) * 64 + l;
        const float o0 = ob[cell * 3 + 0];
        const float o1 = ob[cell * 3 + 1];
        const float o2 = ob[cell * 3 + 2];
        p[k]    = fmaxf(fmaf(o2, w20, fmaf(o1, w10, fmaf(o0, w00, bp0))), 0.f);
        rin[k]  = fmaxf(fmaf(o2, w21, fmaf(o1, w11, fmaf(o0, w01, bp1))), 0.f);
        rout[k] = fmaxf(fmaf(o2, w22, fmaf(o1, w12, fmaf(o0, w02, bp2))), 0.f);
        if (o1 > 0.5f) agent_pos = cell;   // one-hot agent: single writer
    }

    // Static rin boundary rows (rows 8w-1 / 8w+8), once.
    rbnd[0][w][l] = rin[0];
    rbnd[1][w][l] = rin[7];
    __syncthreads();
    const float rinU_b = (w > 0) ? rbnd[1][w - 1][l] : 0.f;
    const float rinD_b = (w < 7) ? rbnd[0][w + 1][l] : 0.f;

    // Fold rout into per-direction reward terms: aX[k] = rin(neighbor X) - rout[k].
    // Out-of-grid terms become -rout <= 0 and can never win the max (v >= 0
    // monotone, p/rin/rout >= 0 from relu, DPP zero-fill at wave edges).
    float aU[8], aD[8], aL[8], aR[8], v[8];
    #pragma unroll
    for (int k = 0; k < 8; ++k) {
        aU[k] = ((k > 0) ? rin[k - 1] : rinU_b) - rout[k];
        aD[k] = ((k < 7) ? rin[k + 1] : rinD_b) - rout[k];
        aL[k] = shr1(rin[k]) - rout[k];
        aR[k] = shl1(rin[k]) - rout[k];
    }

    // Iter 0 peeled: v==0 everywhere -> every p*v term is 0, boundaries 0.
    #pragma unroll
    for (int k = 0; k < 8; ++k)
        v[k] = fmaxf(0.f, fmaxf(fmaxf(aU[k], aD[k]), fmaxf(aL[k], aR[k])));
    // Boundary rows produced by iter 0 -> bnd[0]. (bnd untouched before here.)
    bnd[0][0][w][l] = v[0];
    bnd[0][1][w][l] = v[7];

    // Iters 1..9. Iter it reads bnd[(it-1)&1], writes bnd[it&1] (the slot it
    // overwrites was last read at iter it-1, separated by this iter's barrier).
    for (int it = 1; it < K_ITERS; ++it) {
        const int rd = (it - 1) & 1, wr = it & 1;
        __syncthreads();
        const float vU_b = (w > 0) ? bnd[rd][1][w - 1][l] : 0.f;
        const float vD_b = (w < 7) ? bnd[rd][0][w + 1][l] : 0.f;

        const float ov7 = v[7];
        {   // k = 7 first: uses old v[6] (untouched) and vD_b; store early.
            const float vk = ov7;
            const float vL = shr1(vk), vR = shl1(vk);
            const float tU = fmaf(p[7], v[6], aU[7]);
            const float tD = fmaf(p[7], vD_b, aD[7]);
            const float tL = fmaf(p[7], vL, aL[7]);
            const float tR = fmaf(p[7], vR, aR[7]);
            v[7] = fmaxf(vk, fmaxf(fmaxf(tU, tD), fmaxf(tL, tR)));
            bnd[wr][1][w][l] = v[7];
        }
        const float ov0 = v[0];
        {   // k = 0: uses vU_b and old v[1]; store early.
            const float vk = ov0;
            const float vL = shr1(vk), vR = shl1(vk);
            const float tU = fmaf(p[0], vU_b, aU[0]);
            const float tD = fmaf(p[0], v[1], aD[0]);
            const float tL = fmaf(p[0], vL, aL[0]);
            const float tR = fmaf(p[0], vR, aR[0]);
            v[0] = fmaxf(vk, fmaxf(fmaxf(tU, tD), fmaxf(tL, tR)));
            bnd[wr][0][w][l] = v[0];
        }
        // k = 1..6: vm1 chain carries the OLD previous row; k=6 uses ov7.
        float vm1 = ov0;
        #pragma unroll
        for (int k = 1; k < 7; ++k) {
            const float vk  = v[k];
            const float vp1 = (k < 6) ? v[k + 1] : ov7;
            const float vL  = shr1(vk), vR = shl1(vk);
            const float tU  = fmaf(p[k], vm1, aU[k]);
            const float tD  = fmaf(p[k], vp1, aD[k]);
            const float tL  = fmaf(p[k], vL, aL[k]);
            const float tR  = fmaf(p[k], vR, aR[k]);
            v[k] = fmaxf(vk, fmaxf(fmaxf(tU, tD), fmaxf(tL, tR)));
            vm1 = vk;
        }
    }

    #pragma unroll
    for (int k = 0; k < 8; ++k) v_s[(8 * w + k) * 64 + l] = v[k];
    __syncthreads();

    // 36 features: 3x3 zero-padded windows of (1-walls), agent, goal, v.
    if (tid < 36) {
        const int ap = agent_pos;
        const int ar = ap >> 6, ac = ap & 63;
        const int g  = tid / 9, o = tid % 9;
        const int rr = ar + o / 3 - 1;
        const int cc = ac + o % 3 - 1;
        float val = 0.f;
        if (rr >= 0 && rr < 64 && cc >= 0 && cc < 64) {
            const int cell = rr * 64 + cc;
            if      (g == 0) val = 1.f - ob[cell * 3 + 0];
            else if (g == 1) val = ob[cell * 3 + 1];
            else if (g == 2) val = ob[cell * 3 + 2];
            else             val = v_s[cell];
        }
        feats_out[b * 36 + tid] = val;
    }
}

__global__ __launch_bounds__(1024) void vin_mlp_kernel(
    const float* __restrict__ feats,   // [B,36]
    const float* __restrict__ W1,      // [36,256]
    const float* __restrict__ b1,      // [256]
    const float* __restrict__ W2,      // [256,256]
    const float* __restrict__ b2,      // [256]
    const float* __restrict__ Wl,      // [256,5]
    const float* __restrict__ bl,      // [5]
    float* __restrict__ out)           // [B,5]
{
    const int b0  = blockIdx.x * 4;    // 4 samples per block
    const int tid = threadIdx.x;
    const int c   = tid & 255;         // output column
    const int q   = tid >> 8;          // K-quarter 0..3

    __shared__ float f_s[4][36];
    __shared__ float part[4][4][256];              // [quarter][sample][col] 16KB
    __shared__ __align__(16) float h1_s[256][4];   // [col][sample] 4KB
    __shared__ __align__(16) float h2_s[4][256];   // 4KB
    __shared__ float red[16][4][5];                // 1.25KB

    if (tid < 144) f_s[tid / 36][tid % 36] = feats[b0 * 36 + tid];
    __syncthreads();

    // 36 -> 256 (linear), split-K: quarter q sums rows [9q, 9q+9)
    {
        float a0 = 0.f, a1 = 0.f, a2 = 0.f, a3 = 0.f;
        #pragma unroll
        for (int m = 0; m < 9; ++m) {
            const int i = 9 * q + m;
            const float wv = W1[i * 256 + c];
            a0 = fmaf(f_s[0][i], wv, a0);
            a1 = fmaf(f_s[1][i], wv, a1);
            a2 = fmaf(f_s[2][i], wv, a2);
            a3 = fmaf(f_s[3][i], wv, a3);
        }
        part[q][0][c] = a0; part[q][1][c] = a1;
        part[q][2][c] = a2; part[q][3][c] = a3;
    }
    __syncthreads();
    // combine: thread (c,q) produces sample s=q
    h1_s[c][q] = b1[c] + ((part[0][q][c] + part[1][q][c]) +
                          (part[2][q][c] + part[3][q][c]));
    __syncthreads();

    // 256 -> 256 (linear), split-K: quarter q sums rows [64q, 64q+64)
    {
        float a0 = 0.f, a1 = 0.f, a2 = 0.f, a3 = 0.f;
        #pragma unroll 8
        for (int m = 0; m < 64; ++m) {
            const int i = 64 * q + m;
            const float wv = W2[i * 256 + c];
            const float4 hv = *reinterpret_cast<const float4*>(&h1_s[i][0]); // bcast
            a0 = fmaf(hv.x, wv, a0);
            a1 = fmaf(hv.y, wv, a1);
            a2 = fmaf(hv.z, wv, a2);
            a3 = fmaf(hv.w, wv, a3);
        }
        part[q][0][c] = a0; part[q][1][c] = a1;
        part[q][2][c] = a2; part[q][3][c] = a3;
    }
    __syncthreads();
    h2_s[q][c] = b2[c] + ((part[0][q][c] + part[1][q][c]) +
                          (part[2][q][c] + part[3][q][c]));
    __syncthreads();

    // 256 -> 5: 320 threads, each sums a 16-wide chunk for one (sample,logit)
    if (tid < 320) {
        const int s  = tid & 3;
        const int j  = (tid >> 2) % 5;
        const int ch = tid / 20;        // 0..15
        float acc = 0.f;
        #pragma unroll
        for (int m = 0; m < 16; ++m) {
            const int i = ch * 16 + m;
            acc = fmaf(h2_s[s][i], Wl[i * 5 + j], acc);
        }
        red[ch][s][j] = acc;
    }
    __syncthreads();
    if (tid < 20) {
        const int s = tid & 3;
        const int j = tid >> 2;
        float o = bl[j];
        #pragma unroll
        for (int ch = 0; ch < 16; ++ch) o += red[ch][s][j];
        out[(b0 + s) * 5 + j] = o;
    }
}

extern "C" void kernel_launch(void* const* d_in, const int* in_sizes, int n_in,
                              void* d_out, int out_size, void* d_ws, size_t ws_size,
                              hipStream_t stream) {
    const float* obs   = (const float*)d_in[0];
    const float* W_phi = (const float*)d_in[1];
    const float* b_phi = (const float*)d_in[2];
    const float* W1    = (const float*)d_in[3];
    const float* b1    = (const float*)d_in[4];
    const float* W2    = (const float*)d_in[5];
    const float* b2    = (const float*)d_in[6];
    const float* Wl    = (const float*)d_in[7];
    const float* bl    = (const float*)d_in[8];
    float* out   = (float*)d_out;
    float* feats = (float*)d_ws;   // 1024*36*4 = 147456 bytes

    vin_vi_kernel<<<dim3(1024), dim3(512), 0, stream>>>(obs, W_phi, b_phi, feats);
    vin_mlp_kernel<<<dim3(256), dim3(1024), 0, stream>>>(feats, W1, b1, W2, b2, Wl, bl, out);
}